// Round 3
// baseline (501.362 us; speedup 1.0000x reference)
//
#include <hip/hip_runtime.h>
#include <hip/hip_bf16.h>

#define BATCH 4096
#define TT 60
#define FF 158
#define HH 32
#define GG 96   // 3*H

__device__ __forceinline__ float fexp(float x) {
    return __builtin_amdgcn_exp2f(x * 1.442695040888963f);
}
__device__ __forceinline__ float fsigmoid(float x) {
    return __builtin_amdgcn_rcpf(1.0f + fexp(-x));
}
__device__ __forceinline__ float ftanh(float x) {
    float e = fexp(2.0f * x);
    return (e - 1.0f) * __builtin_amdgcn_rcpf(e + 1.0f);
}

// ---------------------------------------------------------------------------
// K1: gs[tc][b][g] = sum_f x[b][t0+tc][f] * w_ih[g][f]
// Grid: (BATCH*Tc/64) blocks of 256. Each block: 64 rows (row = lane),
// 4 waves x 24 columns each. w_ih read via wave-uniform scalar loads,
// x staged transposed in LDS ([k][row] -> conflict-free b32 reads).
// ---------------------------------------------------------------------------
__global__ __launch_bounds__(256, 4) void k1_gemm(
    const float* __restrict__ x, const float* __restrict__ w_ih,
    float* __restrict__ gs, int t0, int Tc)
{
    __shared__ float xs[FF][64];   // 40448 B
    const int tid  = threadIdx.x;
    const int lane = tid & 63;
    const int wave = tid >> 6;
    const int g0   = __builtin_amdgcn_readfirstlane(wave * 24);  // force SGPR

    const int r0 = blockIdx.x * 64;

    // stage 64 rows x 158 floats as float2 (rows are 8B-aligned: 632B stride)
    for (int i = tid; i < 64 * 79; i += 256) {
        int rr = i & 63;
        int c2 = i >> 6;                 // 0..78
        int R  = r0 + rr;
        int b  = R / Tc;
        int tc = R - b * Tc;
        const float* src = x + ((size_t)b * TT + (size_t)(t0 + tc)) * FF + c2 * 2;
        float2 v = *(const float2*)src;
        xs[c2 * 2][rr]     = v.x;
        xs[c2 * 2 + 1][rr] = v.y;
    }
    __syncthreads();

    float acc[24];
    #pragma unroll
    for (int c = 0; c < 24; ++c) acc[c] = 0.0f;

    const float* wbase = w_ih + (size_t)g0 * FF;

    for (int kc = 0; kc + 4 <= FF; kc += 4) {
        float x0 = xs[kc    ][lane];
        float x1 = xs[kc + 1][lane];
        float x2 = xs[kc + 2][lane];
        float x3 = xs[kc + 3][lane];
        #pragma unroll
        for (int c = 0; c < 24; ++c) {
            const float* w = wbase + c * FF + kc;   // uniform -> s_load
            acc[c] = fmaf(x0, w[0], acc[c]);
            acc[c] = fmaf(x1, w[1], acc[c]);
            acc[c] = fmaf(x2, w[2], acc[c]);
            acc[c] = fmaf(x3, w[3], acc[c]);
        }
    }
    { // tail: k = 156, 157
        float x0 = xs[156][lane];
        float x1 = xs[157][lane];
        #pragma unroll
        for (int c = 0; c < 24; ++c) {
            const float* w = wbase + c * FF + 156;
            acc[c] = fmaf(x0, w[0], acc[c]);
            acc[c] = fmaf(x1, w[1], acc[c]);
        }
    }

    int R  = r0 + lane;
    int b  = R / Tc;
    int tc = R - b * Tc;
    float* dst = gs + ((size_t)tc * BATCH + b) * GG + g0;
    #pragma unroll
    for (int c = 0; c < 24; c += 4) {
        *(float4*)(dst + c) = make_float4(acc[c], acc[c+1], acc[c+2], acc[c+3]);
    }
}

// ---------------------------------------------------------------------------
// K2: GRU recurrence over one t-chunk + (on last chunk) the MLP head.
// Grid: BATCH/8 blocks of 256. Thread = (b_local = tid>>5, j = tid&31).
// w_hh rows {j, j+32, j+64} live in 96 VGPRs. h exchanged via padded LDS.
// gi prefetched one timestep ahead.
// ---------------------------------------------------------------------------
__global__ __launch_bounds__(256, 2) void k2_rec(
    const float* __restrict__ gs, const float* __restrict__ w_hh,
    float* __restrict__ hio, int Tc, int first, int last,
    const float* __restrict__ w1, const float* __restrict__ b1,
    const float* __restrict__ w2, float* __restrict__ out)
{
    __shared__ float hs[8][36];   // padded: conflict-free
    __shared__ float ys[8][16];
    const int tid = threadIdx.x;
    const int bl  = tid >> 5;
    const int j   = tid & 31;
    const int b   = blockIdx.x * 8 + bl;

    float wr[32], wz[32], wn[32];
    #pragma unroll
    for (int kk = 0; kk < 8; ++kk) {
        float4 a = *(const float4*)&w_hh[(size_t)(j     ) * HH + kk * 4];
        float4 c = *(const float4*)&w_hh[(size_t)(j + 32) * HH + kk * 4];
        float4 d = *(const float4*)&w_hh[(size_t)(j + 64) * HH + kk * 4];
        wr[kk*4] = a.x; wr[kk*4+1] = a.y; wr[kk*4+2] = a.z; wr[kk*4+3] = a.w;
        wz[kk*4] = c.x; wz[kk*4+1] = c.y; wz[kk*4+2] = c.z; wz[kk*4+3] = c.w;
        wn[kk*4] = d.x; wn[kk*4+1] = d.y; wn[kk*4+2] = d.z; wn[kk*4+3] = d.w;
    }

    float h = first ? 0.0f : hio[(size_t)b * HH + j];
    hs[bl][j] = h;

    const float* gbase = gs + (size_t)b * GG + j;
    float gir = gbase[0], giz = gbase[32], gin = gbase[64];

    for (int t = 0; t < Tc; ++t) {
        float nir = 0.0f, niz = 0.0f, nin = 0.0f;
        if (t + 1 < Tc) {   // prefetch next timestep's gi
            const float* gnx = gbase + (size_t)(t + 1) * BATCH * GG;
            nir = gnx[0]; niz = gnx[32]; nin = gnx[64];
        }
        __syncthreads();     // hs holds h(t)
        float gr = 0.0f, gz = 0.0f, gn = 0.0f;
        #pragma unroll
        for (int k = 0; k < 32; k += 4) {
            float4 hv = *(const float4*)&hs[bl][k];   // broadcast, aligned
            gr = fmaf(wr[k  ], hv.x, gr); gz = fmaf(wz[k  ], hv.x, gz); gn = fmaf(wn[k  ], hv.x, gn);
            gr = fmaf(wr[k+1], hv.y, gr); gz = fmaf(wz[k+1], hv.y, gz); gn = fmaf(wn[k+1], hv.y, gn);
            gr = fmaf(wr[k+2], hv.z, gr); gz = fmaf(wz[k+2], hv.z, gz); gn = fmaf(wn[k+2], hv.z, gn);
            gr = fmaf(wr[k+3], hv.w, gr); gz = fmaf(wz[k+3], hv.w, gz); gn = fmaf(wn[k+3], hv.w, gn);
        }
        float r = fsigmoid(gir + gr);
        float z = fsigmoid(giz + gz);
        float n = ftanh(gin + r * gn);
        float hnew = (1.0f - z) * n + z * h;
        __syncthreads();     // all reads of hs done
        hs[bl][j] = hnew;
        h = hnew;
        gir = nir; giz = niz; gin = nin;
    }

    if (last) {
        __syncthreads();     // hs holds final h
        if (j < 16) {
            float y = b1[j];
            #pragma unroll
            for (int k = 0; k < 32; ++k) y = fmaf(w1[j * HH + k], hs[bl][k], y);
            ys[bl][j] = fmaxf(y, 0.0f);
        }
        __syncthreads();
        if (j == 0) {
            float o = 0.0f;
            #pragma unroll
            for (int k = 0; k < 16; ++k) o = fmaf(ys[bl][k], w2[k], o);
            out[b] = o;
        }
    } else {
        hio[(size_t)b * HH + j] = h;
    }
}

// ---------------------------------------------------------------------------
extern "C" void kernel_launch(void* const* d_in, const int* in_sizes, int n_in,
                              void* d_out, int out_size, void* d_ws, size_t ws_size,
                              hipStream_t stream)
{
    const float* x    = (const float*)d_in[0];
    const float* w_ih = (const float*)d_in[1];
    const float* w_hh = (const float*)d_in[2];
    const float* w1   = (const float*)d_in[3];
    const float* b1   = (const float*)d_in[4];
    const float* w2   = (const float*)d_in[5];
    float* out = (float*)d_out;

    // workspace: gi chunk [Tc][B][96] fp32 + h carry [B][32] fp32
    const size_t hbytes = (size_t)BATCH * HH * 4;
    size_t avail = (ws_size > hbytes) ? (ws_size - hbytes) : 0;
    int Tc = (int)(avail / ((size_t)BATCH * GG * 4));
    if (Tc > TT) Tc = TT;
    if (Tc < 1) Tc = 1;   // assumes ws_size >= ~2MB

    float* gsbuf = (float*)d_ws;
    float* hio   = (float*)((char*)d_ws + (size_t)BATCH * GG * 4 * (size_t)Tc);

    for (int t0 = 0; t0 < TT; ) {
        int tc = TT - t0; if (tc > Tc) tc = Tc;
        k1_gemm<<<BATCH * tc / 64, 256, 0, stream>>>(x, w_ih, gsbuf, t0, tc);
        int first = (t0 == 0) ? 1 : 0;
        int lastf = (t0 + tc >= TT) ? 1 : 0;
        k2_rec<<<BATCH / 8, 256, 0, stream>>>(gsbuf, w_hh, hio, tc, first, lastf,
                                              w1, b1, w2, out);
        t0 += tc;
    }
}

// Round 6
// 329.482 us; speedup vs baseline: 1.5217x; 1.5217x over previous
//
#include <hip/hip_runtime.h>
#include <hip/hip_bf16.h>

#define BATCH 4096
#define TT 60
#define FF 158
#define HH 32
#define GG 96   // 3*H

typedef float f4 __attribute__((ext_vector_type(4), aligned(4)));
typedef float f2 __attribute__((ext_vector_type(2), aligned(4)));

__device__ __forceinline__ float fexp(float x) {
    return __builtin_amdgcn_exp2f(x * 1.442695040888963f);
}
__device__ __forceinline__ float fsigmoid(float x) {
    return __builtin_amdgcn_rcpf(1.0f + fexp(-x));
}
__device__ __forceinline__ float ftanh(float x) {
    float e = fexp(2.0f * x);
    return (e - 1.0f) * __builtin_amdgcn_rcpf(e + 1.0f);
}

// ---------------------------------------------------------------------------
// K1: gs[tc][b][g] = sum_f x[b][t0+tc][f] * w_ih[g][f]
// 256 thr = 4 waves; block tile 128 rows x 96 cols; wave tile 32 rows.
// Thread micro-tile 8 rows x 6 cols (48 acc). wsT[96][161] staged once
// (one barrier); x tiles wave-private in xs[4][8][132], reg-prefetched one
// K-step ahead -> NO barriers in the K loop (intra-wave DS ordering).
// ---------------------------------------------------------------------------
__global__ __launch_bounds__(256, 2) void k1_gemm(
    const float* __restrict__ x, const float* __restrict__ w_ih,
    float* __restrict__ gs, int t0, int Tc)
{
    __shared__ float wsT[GG][161];     // 61,824 B  (161: conflict-free col reads)
    __shared__ float xs[4][8][132];    // 16,896 B  (132: aligned b128 row reads)

    const int tid  = threadIdx.x;
    const int lane = tid & 63;
    const int wv   = tid >> 6;

    // ---- stage w_ih transposed (coalesced global, conflict-free ds_write)
    for (int i = tid; i < GG * FF; i += 256) {
        int g = i / FF;
        int k = i - g * FF;
        wsT[g][k] = w_ih[i];
    }

    const int tcol = lane & 15;        // 16 col-groups * 6 cols = 96
    const int trow = lane >> 4;        // 4 row-groups * 8 rows  = 32
    const int g0   = tcol * 6;

    // ---- per-lane staging assignment: 32 rows x 8 k per wave tile
    const int srow = lane >> 1;        // 0..31
    const int q    = lane & 1;         // k-half
    const int Rs   = blockIdx.x * 128 + wv * 32 + srow;
    const int bs   = Rs / Tc;
    const int ts   = Rs - bs * Tc;
    const float* xrow = x + ((size_t)bs * TT + (size_t)(t0 + ts)) * FF + q * 4;

    // ---- tile 0
    {
        f4 p0 = *(const f4*)xrow;
        xs[wv][q * 4 + 0][srow] = p0.x;
        xs[wv][q * 4 + 1][srow] = p0.y;
        xs[wv][q * 4 + 2][srow] = p0.z;
        xs[wv][q * 4 + 3][srow] = p0.w;
    }
    __syncthreads();   // wsT ready (xs is wave-private)

    float acc[8][6];
    #pragma unroll
    for (int u = 0; u < 8; ++u)
        #pragma unroll
        for (int i = 0; i < 6; ++i) acc[u][i] = 0.0f;

    // 19 full 8-wide K steps (152) + 6-wide tail = 158
    for (int s = 0; s < 19; ++s) {
        const int  k0n  = (s + 1) * 8;
        const bool tnxt = (s == 18);          // next tile is the 6-wide tail
        f4 pfn; f2 pf2;
        if (!tnxt) {
            pfn = *(const f4*)(xrow + k0n);
        } else {
            if (q == 0) pfn = *(const f4*)(xrow + k0n);   // 152..155
            else        pf2 = *(const f2*)(xrow + k0n);   // 156..157
        }

        const int kbase = s * 8;
        #pragma unroll
        for (int kk = 0; kk < 8; ++kk) {
            const f4 a0 = *(const f4*)&xs[wv][kk][trow * 8];
            const f4 a1 = *(const f4*)&xs[wv][kk][trow * 8 + 4];
            float bv[6];
            #pragma unroll
            for (int i = 0; i < 6; ++i) bv[i] = wsT[g0 + i][kbase + kk];
            #pragma unroll
            for (int i = 0; i < 6; ++i) {
                acc[0][i] = fmaf(a0.x, bv[i], acc[0][i]);
                acc[1][i] = fmaf(a0.y, bv[i], acc[1][i]);
                acc[2][i] = fmaf(a0.z, bv[i], acc[2][i]);
                acc[3][i] = fmaf(a0.w, bv[i], acc[3][i]);
                acc[4][i] = fmaf(a1.x, bv[i], acc[4][i]);
                acc[5][i] = fmaf(a1.y, bv[i], acc[5][i]);
                acc[6][i] = fmaf(a1.z, bv[i], acc[6][i]);
                acc[7][i] = fmaf(a1.w, bv[i], acc[7][i]);
            }
        }

        // write next tile (compiler waits vmcnt; DS in-order per wave)
        if (!tnxt) {
            xs[wv][q * 4 + 0][srow] = pfn.x;
            xs[wv][q * 4 + 1][srow] = pfn.y;
            xs[wv][q * 4 + 2][srow] = pfn.z;
            xs[wv][q * 4 + 3][srow] = pfn.w;
        } else {
            if (q == 0) {
                xs[wv][0][srow] = pfn.x;
                xs[wv][1][srow] = pfn.y;
                xs[wv][2][srow] = pfn.z;
                xs[wv][3][srow] = pfn.w;
            } else {
                xs[wv][4][srow] = pf2.x;
                xs[wv][5][srow] = pf2.y;
            }
        }
    }
    { // tail: k = 152..157 (6 wide)
        #pragma unroll
        for (int kk = 0; kk < 6; ++kk) {
            const f4 a0 = *(const f4*)&xs[wv][kk][trow * 8];
            const f4 a1 = *(const f4*)&xs[wv][kk][trow * 8 + 4];
            float bv[6];
            #pragma unroll
            for (int i = 0; i < 6; ++i) bv[i] = wsT[g0 + i][152 + kk];
            #pragma unroll
            for (int i = 0; i < 6; ++i) {
                acc[0][i] = fmaf(a0.x, bv[i], acc[0][i]);
                acc[1][i] = fmaf(a0.y, bv[i], acc[1][i]);
                acc[2][i] = fmaf(a0.z, bv[i], acc[2][i]);
                acc[3][i] = fmaf(a0.w, bv[i], acc[3][i]);
                acc[4][i] = fmaf(a1.x, bv[i], acc[4][i]);
                acc[5][i] = fmaf(a1.y, bv[i], acc[5][i]);
                acc[6][i] = fmaf(a1.z, bv[i], acc[6][i]);
                acc[7][i] = fmaf(a1.w, bv[i], acc[7][i]);
            }
        }
    }

    // ---- epilogue: 8 rows x 6 cols per thread, float2 stores
    #pragma unroll
    for (int u = 0; u < 8; ++u) {
        int R2 = blockIdx.x * 128 + wv * 32 + trow * 8 + u;
        int b2 = R2 / Tc;
        int t2 = R2 - b2 * Tc;
        float* dst = gs + ((size_t)t2 * BATCH + b2) * GG + g0;
        f2 v0 = {acc[u][0], acc[u][1]};
        f2 v1 = {acc[u][2], acc[u][3]};
        f2 v2 = {acc[u][4], acc[u][5]};
        *(f2*)(dst)     = v0;
        *(f2*)(dst + 2) = v1;
        *(f2*)(dst + 4) = v2;
    }
}

// ---------------------------------------------------------------------------
// K2: GRU recurrence, ZERO barriers. Thread = (b_local, j); each wave owns
// exactly 2 batch rows' hs slots -> wave-synchronous LDS exchange (DS ops are
// in-order per wave; compiler inserts lgkmcnt for the aliasing accesses).
// gi prefetched in 6-step register chunks, double-buffered c0/c1.
// ---------------------------------------------------------------------------
__global__ __launch_bounds__(256, 2) void k2_rec(
    const float* __restrict__ gs, const float* __restrict__ w_hh,
    float* __restrict__ hio, int Tc, int first, int last,
    const float* __restrict__ w1, const float* __restrict__ b1,
    const float* __restrict__ w2, float* __restrict__ out)
{
    __shared__ float hs[8][36];   // padded; wave-private pairs of rows
    __shared__ float ys[8][16];
    const int tid = threadIdx.x;
    const int bl  = tid >> 5;
    const int j   = tid & 31;
    const int b   = blockIdx.x * 8 + bl;

    float wr[32], wz[32], wn[32];
    #pragma unroll
    for (int kk = 0; kk < 8; ++kk) {
        f4 a = *(const f4*)&w_hh[(size_t)(j     ) * HH + kk * 4];
        f4 c = *(const f4*)&w_hh[(size_t)(j + 32) * HH + kk * 4];
        f4 d = *(const f4*)&w_hh[(size_t)(j + 64) * HH + kk * 4];
        wr[kk*4] = a.x; wr[kk*4+1] = a.y; wr[kk*4+2] = a.z; wr[kk*4+3] = a.w;
        wz[kk*4] = c.x; wz[kk*4+1] = c.y; wz[kk*4+2] = c.z; wz[kk*4+3] = c.w;
        wn[kk*4] = d.x; wn[kk*4+1] = d.y; wn[kk*4+2] = d.z; wn[kk*4+3] = d.w;
    }

    float h = first ? 0.0f : hio[(size_t)b * HH + j];
    hs[bl][j] = h;

    const float*  gb = gs + (size_t)b * GG + j;
    const size_t  TS = (size_t)BATCH * GG;

#define K2_STEP(GIR, GIZ, GIN) {                                              \
        float gr = 0.0f, gz = 0.0f, gn = 0.0f;                                \
        _Pragma("unroll")                                                     \
        for (int k = 0; k < 32; k += 4) {                                     \
            f4 hv = *(const f4*)&hs[bl][k];                                   \
            gr = fmaf(wr[k  ], hv.x, gr); gz = fmaf(wz[k  ], hv.x, gz); gn = fmaf(wn[k  ], hv.x, gn); \
            gr = fmaf(wr[k+1], hv.y, gr); gz = fmaf(wz[k+1], hv.y, gz); gn = fmaf(wn[k+1], hv.y, gn); \
            gr = fmaf(wr[k+2], hv.z, gr); gz = fmaf(wz[k+2], hv.z, gz); gn = fmaf(wn[k+2], hv.z, gn); \
            gr = fmaf(wr[k+3], hv.w, gr); gz = fmaf(wz[k+3], hv.w, gz); gn = fmaf(wn[k+3], hv.w, gn); \
        }                                                                     \
        float r = fsigmoid((GIR) + gr);                                       \
        float z = fsigmoid((GIZ) + gz);                                       \
        float n = ftanh((GIN) + r * gn);                                      \
        h = (1.0f - z) * n + z * h;                                           \
        hs[bl][j] = h;                                                        \
    }

    float c0[18], c1[18];
    const int nfull = Tc / 6;

    if (nfull > 0) {
        #pragma unroll
        for (int u = 0; u < 6; ++u) {
            c0[u*3+0] = gb[(size_t)u * TS];
            c0[u*3+1] = gb[(size_t)u * TS + 32];
            c0[u*3+2] = gb[(size_t)u * TS + 64];
        }
    }

    int c = 0;
    while (c < nfull) {
        if (c + 1 < nfull) {
            const int tb = (c + 1) * 6;
            #pragma unroll
            for (int u = 0; u < 6; ++u) {
                c1[u*3+0] = gb[(size_t)(tb+u) * TS];
                c1[u*3+1] = gb[(size_t)(tb+u) * TS + 32];
                c1[u*3+2] = gb[(size_t)(tb+u) * TS + 64];
            }
        }
        #pragma unroll
        for (int u = 0; u < 6; ++u) K2_STEP(c0[u*3], c0[u*3+1], c0[u*3+2]);
        ++c;
        if (c >= nfull) break;

        if (c + 1 < nfull) {
            const int tb = (c + 1) * 6;
            #pragma unroll
            for (int u = 0; u < 6; ++u) {
                c0[u*3+0] = gb[(size_t)(tb+u) * TS];
                c0[u*3+1] = gb[(size_t)(tb+u) * TS + 32];
                c0[u*3+2] = gb[(size_t)(tb+u) * TS + 64];
            }
        }
        #pragma unroll
        for (int u = 0; u < 6; ++u) K2_STEP(c1[u*3], c1[u*3+1], c1[u*3+2]);
        ++c;
    }
    for (int t = nfull * 6; t < Tc; ++t) {   // remainder (Tc not mult of 6)
        float gir = gb[(size_t)t * TS];
        float giz = gb[(size_t)t * TS + 32];
        float gin = gb[(size_t)t * TS + 64];
        K2_STEP(gir, giz, gin);
    }
#undef K2_STEP

    if (last) {
        // head, wave-synchronous (hs written by this same wave)
        if (j < 16) {
            float y = b1[j];
            #pragma unroll
            for (int k = 0; k < 32; ++k) y = fmaf(w1[j * HH + k], hs[bl][k], y);
            ys[bl][j] = fmaxf(y, 0.0f);
        }
        if (j == 0) {
            float o = 0.0f;
            #pragma unroll
            for (int k = 0; k < 16; ++k) o = fmaf(ys[bl][k], w2[k], o);
            out[b] = o;
        }
    } else {
        hio[(size_t)b * HH + j] = h;
    }
}

// ---------------------------------------------------------------------------
extern "C" void kernel_launch(void* const* d_in, const int* in_sizes, int n_in,
                              void* d_out, int out_size, void* d_ws, size_t ws_size,
                              hipStream_t stream)
{
    const float* x    = (const float*)d_in[0];
    const float* w_ih = (const float*)d_in[1];
    const float* w_hh = (const float*)d_in[2];
    const float* w1   = (const float*)d_in[3];
    const float* b1   = (const float*)d_in[4];
    const float* w2   = (const float*)d_in[5];
    float* out = (float*)d_out;

    // workspace: gi chunk [Tc][B][96] fp32 + h carry [B][32] fp32
    const size_t hbytes = (size_t)BATCH * HH * 4;
    size_t avail = (ws_size > hbytes) ? (ws_size - hbytes) : 0;
    int Tc = (int)(avail / ((size_t)BATCH * GG * 4));
    if (Tc > TT) Tc = TT;
    if (Tc < 1) Tc = 1;

    float* gsbuf = (float*)d_ws;
    float* hio   = (float*)((char*)d_ws + (size_t)BATCH * GG * 4 * (size_t)Tc);

    for (int t0 = 0; t0 < TT; ) {
        int tc = TT - t0; if (tc > Tc) tc = Tc;
        k1_gemm<<<BATCH * tc / 128, 256, 0, stream>>>(x, w_ih, gsbuf, t0, tc);
        int first = (t0 == 0) ? 1 : 0;
        int lastf = (t0 + tc >= TT) ? 1 : 0;
        k2_rec<<<BATCH / 8, 256, 0, stream>>>(gsbuf, w_hh, hio, tc, first, lastf,
                                              w1, b1, w2, out);
        t0 += tc;
    }
}